// Round 4
// baseline (504.094 us; speedup 1.0000x reference)
//
#include <hip/hip_runtime.h>
#include <hip/hip_bf16.h>

// Discriminator pipeline. R14 = R13 (plain-launch mega-kernel, hand-rolled
// grid barrier) hardened against the R13 hang (suspected: VGPR>256 =>
// 1 block/CU => 256/512 blocks resident => barrier deadlock => container
// death):
//   1. __launch_bounds__(256,2): compiler MUST fit 2 blocks/CU (VGPR<=256).
//      With 74,752B LDS (<=80KB) both resources now allow 2/CU.
//   2. Host verifies via hipOccupancyMaxActiveBlocksPerMultiprocessor and
//      launches G = min(512, perCU*256); all phase loops are G-agnostic.
//   3. Bounded spin (2^17 x s_sleep(8) ~ 28ms cap): a co-residency failure
//      now produces a fast absmax FAIL (diagnosable) instead of a hang.
// 2 dispatches: init (zero stats+counter) + mega. Phases: A layout+wprep |
// B conv1+BN1stats | D conv2 (BN1+leaky inline on A, 1 A-load : 4 MFMAs)
// +BN2stats | E BN2 apply+transpose | F fc1 (64x576 split-K, LDS-staged A,
// 512 tiles) | G reduce+BN3stats | H fc2+sigmoid.
// MFMA convention (verified m89/m91): D = mfma(a,b,c): D[m][n] = sum_k
// A[m][k]*B[n][k]; a: lane(f=m&15,q=lane>>4) elem j = A[f][q*8+j]; b same
// with f=n; d: lane l reg r = D[(l>>4)*4+r][l&15].
// fc1 LDS row stride 584 u16 = 292 words = 4 mod 32 -> 2-way bank alias only
// (free per m136).

typedef unsigned short u16;
typedef __attribute__((ext_vector_type(8))) short bf8_t;
typedef __attribute__((ext_vector_type(4))) float f4_t;
#define MFMA16(a, b, c) __builtin_amdgcn_mfma_f32_16x16x32_bf16(a, b, c, 0, 0, 0)

#define LEAKY(v) (fmaxf((v), 0.2f * (v)))
#define CLIP01(v) fminf(fmaxf((v), 0.0f), 1.0f)

__device__ inline unsigned f2bf(float f) {  // RNE fp32->bf16 (low 16 bits)
  unsigned u = __float_as_uint(f);
  return (u + 0x7FFFu + ((u >> 16) & 1u)) >> 16;
}
__device__ inline float bf2f(unsigned u) { return __uint_as_float(u << 16); }

// Device-scope grid barrier: all gridDim.x blocks must be co-resident.
// Monotonic counter; k-th barrier waits for target = k*gridDim.x.
// Bounded spin: if co-residency fails we proceed (wrong results, no hang).
__device__ inline void gbar(unsigned* cnt, unsigned target) {
  __syncthreads();
  if (threadIdx.x == 0) {
    __threadfence();  // release: publish this block's stores (agent scope)
    atomicAdd(cnt, 1u);
    unsigned guard = 0;
    while (__hip_atomic_load(cnt, __ATOMIC_RELAXED, __HIP_MEMORY_SCOPE_AGENT) <
           target) {
      __builtin_amdgcn_s_sleep(8);
      if (++guard > (1u << 17)) break;  // ~28ms failsafe
    }
  }
  __syncthreads();
  __threadfence();  // acquire: no stale lines in next phase's reads
}

__global__ __launch_bounds__(256) void init_kernel(float* __restrict__ st,
                                                   unsigned* __restrict__ cnt) {
  for (int i = threadIdx.x; i < 1216; i += 256) st[i] = 0.f;
  if (threadIdx.x == 0) *cnt = 0u;
}

__global__ __launch_bounds__(256, 2) void mega_kernel(
    const float* __restrict__ image, const float* __restrict__ w1,
    const float* __restrict__ w2, const float* __restrict__ g1,
    const float* __restrict__ b1, const float* __restrict__ g2,
    const float* __restrict__ b2, const float* __restrict__ f1w,
    const float* __restrict__ g3, const float* __restrict__ b3,
    const float* __restrict__ f2w, const float* __restrict__ f2b,
    float* __restrict__ out, u16* __restrict__ lay8, u16* __restrict__ x1r,
    u16* __restrict__ x2b, u16* __restrict__ xB, float* __restrict__ part,
    float* __restrict__ fc1o, float* __restrict__ st, u16* __restrict__ wB1,
    u16* __restrict__ wB2, unsigned* __restrict__ cnt) {
  __shared__ __align__(16) char smem[74752];
  const int tid = threadIdx.x;
  const int lane = tid & 63, wv = tid >> 6;
  const int f = lane & 15, q = lane >> 4;
  const int G = gridDim.x;
  const int T = G * 256;  // total threads
  const int W = G * 4;    // total waves
  const int gtid = blockIdx.x * 256 + tid;
  const int gwid = blockIdx.x * 4 + wv;
  unsigned tgt = 0;
  float* bn1sum = st, *bn1sq = st + 32;
  float* bn2sum = st + 64, *bn2sq = st + 128;
  float* bn3sum = st + 192, *bn3sq = st + 704;

  // ---------------- Phase A: weight prep + layout_bbox ----------------------
  for (int i = gtid; i < 58368; i += T) {
    if (i < 7168) {
      int co = i / 224, k = i % 224;
      int chunk = k >> 5, kk = k & 31, tl = kk >> 3, ci = kk & 7;
      int tap = chunk * 4 + tl;
      unsigned v = 0;
      if (tap < 25 && ci < 7) v = f2bf(w1[co * 175 + ci * 25 + tap]);
      wB1[i] = (u16)v;
    } else {
      int jj = i - 7168;  // < 51200
      int tap = jj / 2048, r = jj & 2047, co = r >> 5, ci = r & 31;
      wB2[jj] = (u16)f2bf(w2[co * 800 + ci * 25 + tap]);
    }
  }
  for (int pt = gtid; pt < 746496; pt += T) {
    int b = pt / 11664, rem = pt - b * 11664;
    int h = rem / 108, w = rem - h * 108;
    const float* ib = image + b * 176;
    float best[7];
#pragma unroll
    for (int c = 0; c < 7; ++c) best[c] = 0.f;
    float fw = (float)w, fh = (float)h;
    for (int o = 0; o < 16; ++o) {
      const float* p = ib + o * 11;
      float xc = p[0] * 108.f, yc = p[1] * 108.f;
      float wd = p[2] * 108.f, hd = p[3] * 108.f;
      float x1 = xc - 0.5f * wd, x2 = xc + 0.5f * wd;
      float y1 = yc - 0.5f * hd, y2 = yc + 0.5f * hd;
      float x1d = fw - x1, x2d = x2 - fw;
      float y1d = fh - y1, y2d = y2 - fh;
      float yb = CLIP01(y1d) * CLIP01(y2d);
      float xb = CLIP01(x1d) * CLIP01(x2d);
      float x1l = fmaxf(1.f - fabsf(x1d), 0.f) * yb;
      float x2l = fmaxf(1.f - fabsf(x2d), 0.f) * yb;
      float y1l = fmaxf(1.f - fabsf(y1d), 0.f) * xb;
      float y2l = fmaxf(1.f - fabsf(y2d), 0.f) * xb;
      float xy = fmaxf(fmaxf(x1l, x2l), fmaxf(y1l, y2l));
#pragma unroll
      for (int c = 0; c < 7; ++c) best[c] = fmaxf(best[c], xy * p[4 + c]);
    }
    uint4 stv = {f2bf(best[0]) | (f2bf(best[1]) << 16),
                 f2bf(best[2]) | (f2bf(best[3]) << 16),
                 f2bf(best[4]) | (f2bf(best[5]) << 16), f2bf(best[6])};
    ((uint4*)lay8)[pt] = stv;
  }
  gbar(cnt, tgt += G);

  // ---------------- Phase B: conv1 MFMA + BN1 stats -------------------------
  {
    float sA[2] = {0.f, 0.f}, sQ[2] = {0.f, 0.f};
    for (int it = gwid; it < 2752; it += W) {  // 2752 = 43 mtg * 64 b
      int mtg = it % 43, b = it / 43;
      int pbase[4];
      bool mvalid[4];
#pragma unroll
      for (int t = 0; t < 4; ++t) {
        int mt = mtg * 4 + t;
        mvalid[t] = mt < 169;
        int P = min(mt * 16 + f, 2703);
        int oh = P / 52, ow = P - oh * 52;
        pbase[t] = (oh * 216 + ow * 2) * 8;
      }
      f4_t acc[2][4];
#pragma unroll
      for (int nt = 0; nt < 2; ++nt)
#pragma unroll
        for (int t = 0; t < 4; ++t) acc[nt][t] = {0.f, 0.f, 0.f, 0.f};
      const u16* lb = lay8 + (size_t)b * 93312;
#pragma unroll
      for (int chunk = 0; chunk < 7; ++chunk) {
        int tap = chunk * 4 + q;
        tap = tap > 24 ? 24 : tap;  // dup taps carry zero weights
        int kh = tap / 5, kw = tap - kh * 5;
        int toff = (kh * 108 + kw) * 8;
        bf8_t bf0 = *(const bf8_t*)&wB1[f * 224 + chunk * 32 + q * 8];
        bf8_t bf1 = *(const bf8_t*)&wB1[(16 + f) * 224 + chunk * 32 + q * 8];
#pragma unroll
        for (int t = 0; t < 4; ++t) {
          bf8_t af = *(const bf8_t*)&lb[pbase[t] + toff];
          acc[0][t] = MFMA16(af, bf0, acc[0][t]);
          acc[1][t] = MFMA16(af, bf1, acc[1][t]);
        }
      }
      u16* ob = x1r + (size_t)b * 86528;
#pragma unroll
      for (int t = 0; t < 4; ++t) {
        if (!mvalid[t]) continue;
        int P0 = (mtg * 4 + t) * 16 + q * 4;
#pragma unroll
        for (int nt = 0; nt < 2; ++nt)
#pragma unroll
          for (int r = 0; r < 4; ++r) {
            float v = acc[nt][t][r];
            sA[nt] += v;
            sQ[nt] += v * v;
            ob[(P0 + r) * 32 + nt * 16 + f] = (u16)f2bf(v);
          }
      }
    }
#pragma unroll
    for (int nt = 0; nt < 2; ++nt) {
      sA[nt] += __shfl_xor(sA[nt], 16);
      sA[nt] += __shfl_xor(sA[nt], 32);
      sQ[nt] += __shfl_xor(sQ[nt], 16);
      sQ[nt] += __shfl_xor(sQ[nt], 32);
    }
    float* rs = (float*)smem;  // [4][32]
    float* rq = rs + 128;
    if (lane < 16) {
#pragma unroll
      for (int nt = 0; nt < 2; ++nt) {
        rs[wv * 32 + nt * 16 + f] = sA[nt];
        rq[wv * 32 + nt * 16 + f] = sQ[nt];
      }
    }
    __syncthreads();
    if (tid < 32) {
      atomicAdd(&bn1sum[tid],
                rs[tid] + rs[32 + tid] + rs[64 + tid] + rs[96 + tid]);
      atomicAdd(&bn1sq[tid],
                rq[tid] + rq[32 + tid] + rq[64 + tid] + rq[96 + tid]);
    }
  }
  gbar(cnt, tgt += G);

  // ---------------- Phase D: conv2 MFMA (BN1+leaky inline on A) + BN2 stats -
  {
    float sc1[8], sh1[8];  // channels ci = q*8+j of this lane's A fragments
#pragma unroll
    for (int j = 0; j < 8; ++j) {
      int c = q * 8 + j;
      float mean = bn1sum[c] * (1.f / 173056.f);
      float var = bn1sq[c] * (1.f / 173056.f) - mean * mean;
      float s = g1[c] * rsqrtf(var + 1e-5f);
      sc1[j] = s;
      sh1[j] = b1[c] - mean * s;
    }
    float s2[4] = {0.f, 0.f, 0.f, 0.f}, q2[4] = {0.f, 0.f, 0.f, 0.f};
    for (int it = gwid; it < 2304; it += W) {  // 2304 = 36 mt * 64 b
      int mt = it % 36, b = it / 36;
      int P = mt * 16 + f;
      int oh = P / 24, ow = P - oh * 24;
      int abase = (oh * 104 + ow * 2) * 32 + q * 8;
      const u16* ab = x1r + (size_t)b * 86528;
      f4_t acc[4];
#pragma unroll
      for (int n = 0; n < 4; ++n) acc[n] = {0.f, 0.f, 0.f, 0.f};
#pragma unroll
      for (int tap = 0; tap < 25; ++tap) {
        int kh = tap / 5, kw = tap - kh * 5;
        int toff = (kh * 52 + kw) * 32;
        // A fragment: load raw conv1 bf16, apply BN1+leaky, round to bf16
        uint4 raw = *(const uint4*)&ab[abase + toff];
        unsigned wd[4] = {raw.x, raw.y, raw.z, raw.w};
        union { bf8_t v; u16 u[8]; } r;
#pragma unroll
        for (int k2 = 0; k2 < 4; ++k2) {
          float lo = bf2f(wd[k2] & 0xffffu);
          float hi = bf2f(wd[k2] >> 16);
          lo = LEAKY(fmaf(lo, sc1[2 * k2], sh1[2 * k2]));
          hi = LEAKY(fmaf(hi, sc1[2 * k2 + 1], sh1[2 * k2 + 1]));
          r.u[2 * k2] = (u16)f2bf(lo);
          r.u[2 * k2 + 1] = (u16)f2bf(hi);
        }
        const u16* wp = &wB2[tap * 2048 + f * 32 + q * 8];
#pragma unroll
        for (int n = 0; n < 4; ++n) {  // co = n*16+f -> +n*512 u16
          bf8_t bf = *(const bf8_t*)&wp[n * 512];
          acc[n] = MFMA16(r.v, bf, acc[n]);
        }
      }
      u16* ob = x2b + (size_t)b * 36864;
#pragma unroll
      for (int n = 0; n < 4; ++n)
#pragma unroll
        for (int rr = 0; rr < 4; ++rr) {
          float v = acc[n][rr];
          s2[n] += v;
          q2[n] += v * v;
          ob[(mt * 16 + q * 4 + rr) * 64 + n * 16 + f] = (u16)f2bf(v);
        }
    }
#pragma unroll
    for (int n = 0; n < 4; ++n) {
      s2[n] += __shfl_xor(s2[n], 16);
      s2[n] += __shfl_xor(s2[n], 32);
      q2[n] += __shfl_xor(q2[n], 16);
      q2[n] += __shfl_xor(q2[n], 32);
    }
    float* rs = (float*)smem;  // [4][64]
    float* rq = rs + 256;
    if (lane < 16) {
#pragma unroll
      for (int n = 0; n < 4; ++n) {
        rs[wv * 64 + n * 16 + f] = s2[n];
        rq[wv * 64 + n * 16 + f] = q2[n];
      }
    }
    __syncthreads();
    if (tid < 64) {
      atomicAdd(&bn2sum[tid],
                rs[tid] + rs[64 + tid] + rs[128 + tid] + rs[192 + tid]);
      atomicAdd(&bn2sq[tid],
                rq[tid] + rq[64 + tid] + rq[128 + tid] + rq[192 + tid]);
    }
  }
  gbar(cnt, tgt += G);

  // ---------------- Phase E: BN2 apply + leaky + NHWC->NCHW ----------------
  {
    float* tile = (float*)smem;  // [64][65] floats = 16,640 B
    int c = tid & 63, hl4 = tid >> 6;
    float mean = bn2sum[c] * (1.f / 36864.f);
    float var = bn2sq[c] * (1.f / 36864.f) - mean * mean;
    float s = g2[c] * rsqrtf(var + 1e-5f);
    float hh = b2[c] - mean * s;
    for (int vb = blockIdx.x; vb < 576; vb += G) {  // (9 hw-tiles, 64 b)
      int hw0 = (vb % 9) * 64, b = vb / 9;
      __syncthreads();
#pragma unroll
      for (int itr = 0; itr < 16; ++itr) {
        int hl = itr * 4 + hl4;
        float v = bf2f((unsigned)x2b[((size_t)b * 576 + hw0 + hl) * 64 + c]);
        tile[hl * 65 + c] = LEAKY(fmaf(v, s, hh));
      }
      __syncthreads();
#pragma unroll
      for (int itr = 0; itr < 16; ++itr) {
        int cc = itr * 4 + (tid >> 6);
        xB[(size_t)b * 36864 + cc * 576 + hw0 + (tid & 63)] =
            (u16)f2bf(tile[(tid & 63) * 65 + cc]);
      }
    }
  }
  gbar(cnt, tgt += G);

  // ---------------- Phase F: fc1 MFMA (64-way split-K, 512 tiles) ----------
  {
    u16* sAr = (u16*)smem;  // [64][584] u16 = 74,752 B
    for (int vb = blockIdx.x; vb < 512; vb += G) {
      int ks = vb >> 3, nb = vb & 7;
      int n0 = nb * 64 + wv * 16;
      int kb = ks * 576;
      __syncthreads();
      for (int c = tid; c < 4608; c += 256) {  // 64 rows * 72 uint4
        int row = c / 72, col = c - row * 72;
        *(uint4*)&sAr[row * 584 + col * 8] =
            *(const uint4*)&xB[(size_t)row * 36864 + kb + col * 8];
      }
      __syncthreads();
      f4_t acc[4];
#pragma unroll
      for (int m = 0; m < 4; ++m) acc[m] = {0.f, 0.f, 0.f, 0.f};
      const float* wrow = f1w + (size_t)(n0 + f) * 36864 + kb + q * 8;
#pragma unroll 3
      for (int kt = 0; kt < 18; ++kt) {
        const float* wp = wrow + kt * 32;
        float4 wa = *(const float4*)wp;
        float4 wb = *(const float4*)(wp + 4);
        union { bf8_t v; u16 u[8]; } bu;
        bu.u[0] = (u16)f2bf(wa.x); bu.u[1] = (u16)f2bf(wa.y);
        bu.u[2] = (u16)f2bf(wa.z); bu.u[3] = (u16)f2bf(wa.w);
        bu.u[4] = (u16)f2bf(wb.x); bu.u[5] = (u16)f2bf(wb.y);
        bu.u[6] = (u16)f2bf(wb.z); bu.u[7] = (u16)f2bf(wb.w);
        bf8_t afr[4];
#pragma unroll
        for (int m = 0; m < 4; ++m)
          afr[m] = *(const bf8_t*)&sAr[(m * 16 + f) * 584 + kt * 32 + q * 8];
#pragma unroll
        for (int m = 0; m < 4; ++m) acc[m] = MFMA16(afr[m], bu.v, acc[m]);
      }
      float* pp = part + (size_t)ks * 32768;
#pragma unroll
      for (int m = 0; m < 4; ++m)
#pragma unroll
        for (int r = 0; r < 4; ++r)
          pp[(m * 16 + q * 4 + r) * 512 + n0 + f] = acc[m][r];
    }
  }
  gbar(cnt, tgt += G);

  // ---------------- Phase G: reduce 64 partials + BN3 stats ----------------
  for (int i = gtid; i < 32768; i += T) {
    float s = 0.f;
#pragma unroll 8
    for (int ks2 = 0; ks2 < 64; ++ks2) s += part[(size_t)ks2 * 32768 + i];
    fc1o[i] = s;
    atomicAdd(&bn3sum[i & 511], s);
    atomicAdd(&bn3sq[i & 511], s * s);
  }
  gbar(cnt, tgt += G);

  // ---------------- Phase H: fc2 = BN3 inline + leaky + dot + sigmoid ------
  if (blockIdx.x < 64 && tid < 64) {
    int m = blockIdx.x;
    float a = 0.f;
#pragma unroll
    for (int j = 0; j < 8; ++j) {
      int ff = tid + j * 64;
      float mean = bn3sum[ff] * (1.f / 64.f);
      float var = bn3sq[ff] * (1.f / 64.f) - mean * mean;
      float sc = g3[ff] * rsqrtf(var + 1e-5f);
      float sh = b3[ff] - mean * sc;
      float v = LEAKY(fmaf(fc1o[m * 512 + ff], sc, sh));
      a += v * f2w[ff];
    }
    for (int off = 32; off; off >>= 1) a += __shfl_down(a, off, 64);
    if (tid == 0) out[m] = 1.f / (1.f + expf(-(a + f2b[0])));
  }
}

extern "C" void kernel_launch(void* const* d_in, const int* in_sizes, int n_in,
                              void* d_out, int out_size, void* d_ws,
                              size_t ws_size, hipStream_t stream) {
  const float* image = (const float*)d_in[0];
  const float* c1w = (const float*)d_in[1];
  const float* bn1g = (const float*)d_in[3];
  const float* bn1b = (const float*)d_in[4];
  const float* c2w = (const float*)d_in[5];
  const float* bn2g = (const float*)d_in[7];
  const float* bn2b = (const float*)d_in[8];
  const float* f1w = (const float*)d_in[9];
  const float* bn3g = (const float*)d_in[11];
  const float* bn3b = (const float*)d_in[12];
  const float* f2w = (const float*)d_in[13];
  const float* f2b = (const float*)d_in[14];
  float* ws = (float*)d_ws;
  float* outp = (float*)d_out;

  // Workspace (float units), linear (~41 MB of 302 MB; no aliasing):
  u16* lay8 = (u16*)ws;              // 2,985,984 f
  u16* x1r = (u16*)(ws + 2985984);   // 2,768,896 f
  u16* x2b = (u16*)(ws + 5754880);   // 1,179,648 f
  u16* xB = (u16*)(ws + 6934528);    // 1,179,648 f
  float* part = ws + 8114176;        // 2,097,152 f (64*32768)
  float* fc1o = ws + 10211328;       // 32,768 f
  float* st = ws + 10244096;         // 1,216 f (zeroed by init_kernel)
  unsigned* cnt = (unsigned*)(ws + 10245312);  // barrier counter (16 f pad)
  u16* wB1 = (u16*)(ws + 10245328);  // 7,168 u16
  u16* wB2 = (u16*)(ws + 10248912);  // 51,200 u16

  // Grid sized to guaranteed co-residency (query once; pure host query,
  // graph-capture safe). __launch_bounds__(256,2) targets 2 blocks/CU.
  static int nblk = 0;
  if (nblk == 0) {
    int perCU = 0;
    hipOccupancyMaxActiveBlocksPerMultiprocessor(
        &perCU, reinterpret_cast<const void*>(mega_kernel), 256, 0);
    if (perCU < 1) perCU = 1;
    if (perCU > 2) perCU = 2;
    nblk = perCU * 256;
  }

  init_kernel<<<1, 256, 0, stream>>>(st, cnt);
  mega_kernel<<<nblk, 256, 0, stream>>>(image, c1w, c2w, bn1g, bn1b, bn2g,
                                        bn2b, f1w, bn3g, bn3b, f2w, f2b, outp,
                                        lay8, x1r, x2b, xB, part, fc1o, st,
                                        wB1, wB2, cnt);
}

// Round 5
// 262.365 us; speedup vs baseline: 1.9213x; 1.9213x over previous
//
#include <hip/hip_runtime.h>
#include <hip/hip_bf16.h>

// Discriminator pipeline. R15 = R10 (best verified, 239.4us) with ONE change:
// conv2_lds replaces {bnapply1 + conv2_mfma}. Block=(mt,b) stages the 7x52x32
// x1r slab (23.3KB contiguous -> coalesced) into LDS applying BN1+leaky ONCE
// per element (bit-identical to bnapply1: same f2bf(leaky(fma))), then 25-tap
// MFMA from LDS (kills x1b buffer 22MB + one dispatch + global tap-refetch).
// Mega-kernel experiment (R12-R14) verdict: single-kernel = 504us >> 239us;
// dispatch boundaries are NOT the dominant cost; phase math (incl. BN1
// inline) verified at absmax 0.0039.
// 7 dispatches: layout(+wprep+zero stats) -> conv1(+BN1 stats) ->
// conv2_lds(BN1 inline staging, +BN2 stats) -> bnapply2t -> fc1 (72x512
// split-K) -> fc1_reduce(+BN3 stats) -> fc2 (BN3 inline + sigmoid).
//
// MFMA convention (verified m89/m91): D = mfma(a,b,c): D[m][n] = sum_k
// A[m][k]*B[n][k]; a: lane(f=m&15,q=lane>>4) elem j = A[f][q*8+j]; b same
// with f=n; d: lane l reg r = D[(l>>4)*4+r][l&15].
// fc1 LDS tile pad: row stride 520 u16 = 260 words = 4 mod 32 -> 2-way bank
// alias only (free per m136). Do NOT remove the pad (32-row stride = 8-way).

typedef unsigned short u16;
typedef __attribute__((ext_vector_type(8))) short bf8_t;
typedef __attribute__((ext_vector_type(4))) float f4_t;
#define MFMA16(a, b, c) __builtin_amdgcn_mfma_f32_16x16x32_bf16(a, b, c, 0, 0, 0)

#define LEAKY(v) (fmaxf((v), 0.2f * (v)))
#define CLIP01(v) fminf(fmaxf((v), 0.0f), 1.0f)

__device__ inline unsigned f2bf(float f) {  // RNE fp32->bf16 (low 16 bits)
  unsigned u = __float_as_uint(f);
  return (u + 0x7FFFu + ((u >> 16) & 1u)) >> 16;
}
__device__ inline float bf2f(unsigned u) { return __uint_as_float(u << 16); }

constexpr int HW = 108;
constexpr int NOBJ = 16;
constexpr int NCLS = 7;

// ---------------- layout_bbox -> NHWC8 bf16 (+ weight prep in first 114 blocks)
__global__ __launch_bounds__(128) void layout_prep_kernel(
    const float* __restrict__ image, const float* __restrict__ w1,
    const float* __restrict__ w2, u16* __restrict__ lay8,
    u16* __restrict__ wB1, u16* __restrict__ wB2, float* __restrict__ st) {
  int h = blockIdx.x, b = blockIdx.y;
  int tid = threadIdx.x;
  int bid = b * 108 + h;
  if (bid < 114) {  // 114 * 512 = 58368 prep items
#pragma unroll
    for (int j = 0; j < 4; ++j) {
      int i = bid * 512 + j * 128 + tid;
      if (i < 1216) st[i] = 0.f;
      if (i < 7168) {
        int co = i / 224, k = i % 224;
        int chunk = k >> 5, kk = k & 31, tl = kk >> 3, ci = kk & 7;
        int tap = chunk * 4 + tl;
        unsigned v = 0;
        if (tap < 25 && ci < 7) v = f2bf(w1[co * 175 + ci * 25 + tap]);
        wB1[i] = (u16)v;
      } else if (i < 58368) {
        int jj = i - 7168;  // < 51200
        int tap = jj / 2048, r = jj % 2048, co = r >> 5, ci = r & 31;
        wB2[jj] = (u16)f2bf(w2[co * 800 + ci * 25 + tap]);
      }
    }
  }
  __shared__ float sIm[NOBJ * 11];
  for (int i = tid; i < NOBJ * 11; i += 128) sIm[i] = image[b * NOBJ * 11 + i];
  __syncthreads();
  int w = tid;
  if (w >= HW) return;
  float best[NCLS];
#pragma unroll
  for (int c = 0; c < NCLS; ++c) best[c] = 0.0f;
  float fw = (float)w, fh = (float)h;
  for (int o = 0; o < NOBJ; ++o) {
    const float* p = &sIm[o * 11];
    float xc = p[0] * 108.0f, yc = p[1] * 108.0f;
    float wd = p[2] * 108.0f, hd = p[3] * 108.0f;
    float x1 = xc - 0.5f * wd, x2 = xc + 0.5f * wd;
    float y1 = yc - 0.5f * hd, y2 = yc + 0.5f * hd;
    float x1d = fw - x1, x2d = x2 - fw;
    float y1d = fh - y1, y2d = y2 - fh;
    float yband = CLIP01(y1d) * CLIP01(y2d);
    float xband = CLIP01(x1d) * CLIP01(x2d);
    float x1l = fmaxf(1.0f - fabsf(x1d), 0.0f) * yband;
    float x2l = fmaxf(1.0f - fabsf(x2d), 0.0f) * yband;
    float y1l = fmaxf(1.0f - fabsf(y1d), 0.0f) * xband;
    float y2l = fmaxf(1.0f - fabsf(y2d), 0.0f) * xband;
    float xy = fmaxf(fmaxf(x1l, x2l), fmaxf(y1l, y2l));
#pragma unroll
    for (int c = 0; c < NCLS; ++c) best[c] = fmaxf(best[c], xy * p[4 + c]);
  }
  unsigned p0 = f2bf(best[0]) | (f2bf(best[1]) << 16);
  unsigned p1 = f2bf(best[2]) | (f2bf(best[3]) << 16);
  unsigned p2 = f2bf(best[4]) | (f2bf(best[5]) << 16);
  unsigned p3 = f2bf(best[6]);
  uint4 stv = {p0, p1, p2, p3};
  ((uint4*)lay8)[b * 11664 + h * 108 + w] = stv;
}

// --------------------------------------------------------------- conv1 MFMA
// grid (43 mt4, 2 nt, 16 bz), block 128 = 2 waves.  (R10 exact)
__global__ __launch_bounds__(128) void conv1_mfma(
    const u16* __restrict__ lay8, const u16* __restrict__ wB1,
    u16* __restrict__ x1r, float* __restrict__ bn1sum,
    float* __restrict__ bn1sq) {
  int mtg = blockIdx.x, nt = blockIdx.y, bz = blockIdx.z;
  int tid = threadIdx.x;
  int lane = tid & 63, wv = tid >> 6;
  int f = lane & 15, q = lane >> 4;
  int co = nt * 16 + f;
  int b0 = bz * 4 + wv * 2;
  int pbase[4];
  bool mvalid[4];
#pragma unroll
  for (int t = 0; t < 4; ++t) {
    int mt = mtg * 4 + t;
    mvalid[t] = mt < 169;
    int P = min(mt * 16 + f, 2703);
    int oh = P / 52, ow = P - oh * 52;
    pbase[t] = (oh * 2 * 108 + ow * 2) * 8;
  }
  f4_t acc[2][4];
#pragma unroll
  for (int b2 = 0; b2 < 2; ++b2)
#pragma unroll
    for (int t = 0; t < 4; ++t) acc[b2][t] = {0.f, 0.f, 0.f, 0.f};
#pragma unroll
  for (int chunk = 0; chunk < 7; ++chunk) {
    int tap = chunk * 4 + q;
    tap = tap > 24 ? 24 : tap;  // dup taps carry zero weights
    int kh = tap / 5, kw = tap - kh * 5;
    int toff = (kh * 108 + kw) * 8;
    bf8_t bf = *(const bf8_t*)&wB1[co * 224 + chunk * 32 + q * 8];
#pragma unroll
    for (int b2 = 0; b2 < 2; ++b2) {
      const u16* lb = lay8 + (size_t)(b0 + b2) * 93312;
#pragma unroll
      for (int t = 0; t < 4; ++t) {
        bf8_t af = *(const bf8_t*)&lb[pbase[t] + toff];
        acc[b2][t] = MFMA16(af, bf, acc[b2][t]);
      }
    }
  }
  float s = 0.f, sq = 0.f;
#pragma unroll
  for (int b2 = 0; b2 < 2; ++b2) {
    u16* ob = x1r + (size_t)(b0 + b2) * 86528;
#pragma unroll
    for (int t = 0; t < 4; ++t) {
      if (!mvalid[t]) continue;
      int P0 = (mtg * 4 + t) * 16 + q * 4;
#pragma unroll
      for (int r = 0; r < 4; ++r) {
        float v = acc[b2][t][r];
        s += v;
        sq += v * v;
        ob[(P0 + r) * 32 + co] = (u16)f2bf(v);
      }
    }
  }
  s += __shfl_xor(s, 16);
  s += __shfl_xor(s, 32);
  sq += __shfl_xor(sq, 16);
  sq += __shfl_xor(sq, 32);
  __shared__ float rs[2][16], rq[2][16];
  if (lane < 16) {
    rs[wv][f] = s;
    rq[wv][f] = sq;
  }
  __syncthreads();
  if (tid < 16) {
    atomicAdd(&bn1sum[nt * 16 + tid], rs[0][tid] + rs[1][tid]);
    atomicAdd(&bn1sq[nt * 16 + tid], rq[0][tid] + rq[1][tid]);
  }
}

// ------------------------------------------------ conv2 (LDS, BN1 inline)
// grid (36 mt, 64 b), block 256 = 4 waves. Stage x1r rows [2*oh0, +7) x 52 x
// 32ch (contiguous 23.3KB) into LDS with BN1+leaky applied ONCE per element
// (bit-identical to old bnapply1). Wave wv computes co = wv*16+f over 25
// taps from LDS. BN2 stats: one co per lane-group -> direct atomics.
__global__ __launch_bounds__(256) void conv2_lds(
    const u16* __restrict__ x1r, const u16* __restrict__ wB2,
    const float* __restrict__ bn1sum, const float* __restrict__ bn1sq,
    const float* __restrict__ g1, const float* __restrict__ b1,
    u16* __restrict__ x2b, float* __restrict__ bn2sum,
    float* __restrict__ bn2sq) {
  int mt = blockIdx.x, b = blockIdx.y;
  int tid = threadIdx.x;
  int lane = tid & 63, wv = tid >> 6;
  int f = lane & 15, q = lane >> 4;
  __shared__ u16 sA[7 * 52 * 32];  // 23,296 B
  __shared__ float rsm[64], rqm[64];
  int oh0 = (mt * 16) / 24;
  int base = 2 * oh0;
  // Staging: chunk ci (uint4 = 8 consecutive channels); ci = tid + 256*it so
  // channel octet = (tid&3)*8 is per-thread constant -> 8 sc/sh registers.
  {
    float sc1[8], sh1[8];
    int oc = (tid & 3) * 8;
#pragma unroll
    for (int j = 0; j < 8; ++j) {
      int c = oc + j;
      float mean = bn1sum[c] * (1.f / 173056.f);
      float var = bn1sq[c] * (1.f / 173056.f) - mean * mean;
      float s = g1[c] * rsqrtf(var + 1e-5f);
      sc1[j] = s;
      sh1[j] = b1[c] - mean * s;
    }
    const u16* xb = x1r + (size_t)b * 86528;
#pragma unroll
    for (int it = 0; it < 6; ++it) {
      int ci = it * 256 + tid;  // < 1456 = 7 rows * 208 uint4
      if (ci < 1456) {
        int r = ci / 208, k = ci - r * 208;
        int gr = base + r;
        gr = gr > 51 ? 51 : gr;  // clamp (dup row never read by taps)
        uint4 raw = *(const uint4*)&xb[gr * 1664 + k * 8];
        unsigned wd[4] = {raw.x, raw.y, raw.z, raw.w};
        unsigned out[4];
#pragma unroll
        for (int k2 = 0; k2 < 4; ++k2) {
          float lo = bf2f(wd[k2] & 0xffffu);
          float hi = bf2f(wd[k2] >> 16);
          lo = LEAKY(fmaf(lo, sc1[2 * k2], sh1[2 * k2]));
          hi = LEAKY(fmaf(hi, sc1[2 * k2 + 1], sh1[2 * k2 + 1]));
          out[k2] = f2bf(lo) | (f2bf(hi) << 16);
        }
        uint4 stv = {out[0], out[1], out[2], out[3]};
        *(uint4*)&sA[r * 1664 + k * 8] = stv;
      }
    }
  }
  __syncthreads();
  int P = mt * 16 + f;
  int oh = P / 24, ow = P - oh * 24;
  int drow = 2 * oh - base;  // 0 or 2
  int co = wv * 16 + f;
  f4_t acc = {0.f, 0.f, 0.f, 0.f};
#pragma unroll
  for (int tap = 0; tap < 25; ++tap) {
    int kh = tap / 5, kw = tap - kh * 5;
    bf8_t af =
        *(const bf8_t*)&sA[(drow + kh) * 1664 + (2 * ow + kw) * 32 + q * 8];
    bf8_t bf = *(const bf8_t*)&wB2[tap * 2048 + co * 32 + q * 8];
    acc = MFMA16(af, bf, acc);
  }
  u16* ob = x2b + (size_t)b * 36864;
  float s = 0.f, sq = 0.f;
#pragma unroll
  for (int rr = 0; rr < 4; ++rr) {
    float v = acc[rr];
    s += v;
    sq += v * v;
    ob[(mt * 16 + q * 4 + rr) * 64 + co] = (u16)f2bf(v);
  }
  s += __shfl_xor(s, 16);
  s += __shfl_xor(s, 32);
  sq += __shfl_xor(sq, 16);
  sq += __shfl_xor(sq, 32);
  if (lane < 16) {  // q==0 lane holds the co-total for this block item
    rsm[wv * 16 + lane] = s;
    rqm[wv * 16 + lane] = sq;
  }
  __syncthreads();
  if (tid < 64) {
    atomicAdd(&bn2sum[tid], rsm[tid]);
    atomicAdd(&bn2sq[tid], rqm[tid]);
  }
}

// ---- BN2 finalize(inline)+leaky + NHWC->NCHW: x2b bf16 -> xB bf16 [b][64*576]
__global__ __launch_bounds__(256) void bnapply2t_kernel(
    const u16* __restrict__ x2b, const float* __restrict__ bn2sum,
    const float* __restrict__ bn2sq, const float* __restrict__ g2,
    const float* __restrict__ b2, u16* __restrict__ xB) {
  int hw0 = blockIdx.x * 64, b = blockIdx.y;
  __shared__ float tile[64 * 65];
  int t = threadIdx.x;
  int c = t & 63, hl4 = t >> 6;
  float mean = bn2sum[c] * (1.f / 36864.f);
  float var = bn2sq[c] * (1.f / 36864.f) - mean * mean;
  float s = g2[c] * rsqrtf(var + 1e-5f);
  float h = b2[c] - mean * s;
#pragma unroll
  for (int it = 0; it < 16; ++it) {
    int hl = it * 4 + hl4;
    float v = bf2f((unsigned)x2b[((size_t)b * 576 + hw0 + hl) * 64 + c]);
    tile[hl * 65 + c] = LEAKY(fmaf(v, s, h));
  }
  __syncthreads();
  int hw = t & 63, cl4 = t >> 6;
#pragma unroll
  for (int it = 0; it < 16; ++it) {
    int cc = it * 4 + cl4;
    xB[(size_t)b * 36864 + cc * 576 + hw0 + hw] = (u16)f2bf(tile[hw * 65 + cc]);
  }
}

// ----------------------------------------------------------------- fc1 MFMA
// part[ks][64][512]: A bf16 [64][36864] x W fp32[512][36864] (cvt in-flight).
// grid (72 ks, 8 nb), block 256 = 4 waves; A staged once (row pad 520 u16 ->
// 2-way bank alias only); K loop barrier-free.  (R10 exact)
__global__ __launch_bounds__(256) void fc1_mfma(
    const u16* __restrict__ xB, const float* __restrict__ wgt,
    float* __restrict__ part) {
  int ks = blockIdx.x, nb = blockIdx.y;
  int tid = threadIdx.x;
  int lane = tid & 63, wv = tid >> 6;
  int f = lane & 15, q = lane >> 4;
  int n0 = nb * 64 + wv * 16;
  int kbase = ks * 512;
  __shared__ u16 sA[64 * 520];
#pragma unroll
  for (int i = 0; i < 16; ++i) {
    int c = i * 256 + tid;           // 0..4095
    int row = c >> 6, col = c & 63;  // col in uint4 (8-u16) units
    *(uint4*)&sA[row * 520 + col * 8] =
        *(const uint4*)&xB[(size_t)row * 36864 + kbase + col * 8];
  }
  __syncthreads();
  f4_t acc[4];
#pragma unroll
  for (int m = 0; m < 4; ++m) acc[m] = {0.f, 0.f, 0.f, 0.f};
  const float* wrow = wgt + (size_t)(n0 + f) * 36864 + kbase + q * 8;
#pragma unroll 4
  for (int kt = 0; kt < 16; ++kt) {
    const float* wp = wrow + kt * 32;
    float4 wa = *(const float4*)wp;
    float4 wb = *(const float4*)(wp + 4);
    union { bf8_t v; u16 u[8]; } bu;
    bu.u[0] = (u16)f2bf(wa.x); bu.u[1] = (u16)f2bf(wa.y);
    bu.u[2] = (u16)f2bf(wa.z); bu.u[3] = (u16)f2bf(wa.w);
    bu.u[4] = (u16)f2bf(wb.x); bu.u[5] = (u16)f2bf(wb.y);
    bu.u[6] = (u16)f2bf(wb.z); bu.u[7] = (u16)f2bf(wb.w);
    bf8_t afr[4];
#pragma unroll
    for (int m = 0; m < 4; ++m)
      afr[m] = *(const bf8_t*)&sA[(m * 16 + f) * 520 + kt * 32 + q * 8];
#pragma unroll
    for (int m = 0; m < 4; ++m) acc[m] = MFMA16(afr[m], bu.v, acc[m]);
  }
  float* pp = part + (size_t)ks * 32768;
#pragma unroll
  for (int m = 0; m < 4; ++m)
#pragma unroll
    for (int r = 0; r < 4; ++r)
      pp[(m * 16 + q * 4 + r) * 512 + n0 + f] = acc[m][r];
}

// --------------- fc1_reduce: sum 72 partials -> fc1o; fused BN3 stat atomics
__global__ __launch_bounds__(256) void fc1_reduce_kernel(
    const float* __restrict__ part, float* __restrict__ fc1o,
    float* __restrict__ bn3sum, float* __restrict__ bn3sq) {
  int i = blockIdx.x * 256 + threadIdx.x;  // 0..32767
  float s = 0.f;
#pragma unroll 8
  for (int ks = 0; ks < 72; ++ks) s += part[(size_t)ks * 32768 + i];
  fc1o[i] = s;
  atomicAdd(&bn3sum[i & 511], s);
  atomicAdd(&bn3sq[i & 511], s * s);
}

// ------------------------- fc2: BN3 inline + leaky + dot + sigmoid
__global__ __launch_bounds__(64) void fc2_kernel(
    const float* __restrict__ fc1o, const float* __restrict__ bn3sum,
    const float* __restrict__ bn3sq, const float* __restrict__ g3,
    const float* __restrict__ b3, const float* __restrict__ w2,
    const float* __restrict__ b2o, float* __restrict__ out) {
  int m = blockIdx.x;
  int fl = threadIdx.x;
  float a = 0.f;
#pragma unroll
  for (int j = 0; j < 8; ++j) {
    int ff = fl + j * 64;
    float mean = bn3sum[ff] * (1.f / 64.f);
    float var = bn3sq[ff] * (1.f / 64.f) - mean * mean;
    float sc = g3[ff] * rsqrtf(var + 1e-5f);
    float sh = b3[ff] - mean * sc;
    float v = LEAKY(fmaf(fc1o[m * 512 + ff], sc, sh));
    a += v * w2[ff];
  }
  for (int off = 32; off; off >>= 1) a += __shfl_down(a, off, 64);
  if (fl == 0) out[m] = 1.f / (1.f + expf(-(a + b2o[0])));
}

extern "C" void kernel_launch(void* const* d_in, const int* in_sizes, int n_in,
                              void* d_out, int out_size, void* d_ws,
                              size_t ws_size, hipStream_t stream) {
  const float* image = (const float*)d_in[0];
  const float* c1w = (const float*)d_in[1];
  const float* bn1g = (const float*)d_in[3];
  const float* bn1b = (const float*)d_in[4];
  const float* c2w = (const float*)d_in[5];
  const float* bn2g = (const float*)d_in[7];
  const float* bn2b = (const float*)d_in[8];
  const float* f1w = (const float*)d_in[9];
  const float* bn3g = (const float*)d_in[11];
  const float* bn3b = (const float*)d_in[12];
  const float* f2w = (const float*)d_in[13];
  const float* f2b = (const float*)d_in[14];
  float* ws = (float*)d_ws;

  // Workspace (float units), linear (R10 layout; x1b slot unused now):
  u16* lay8 = (u16*)ws;                    // @0          (2,985,984 f)
  u16* x1r = (u16*)(ws + 2985984);         // 2,768,896 f
  u16* x2b = (u16*)(ws + 8523776);         // 1,179,648 f
  u16* xB = (u16*)(ws + 9703424);          // 1,179,648 f
  float* fc1part = ws + 10883072;          // 2,359,296 f (72*32768)
  float* fc1o = ws + 13242368;             // 32,768 f
  float* st = ws + 13275136;               // 1,216 f (zeroed by layout_prep)
  float* bn1sum = st, *bn1sq = st + 32;
  float* bn2sum = st + 64, *bn2sq = st + 128;
  float* bn3sum = st + 192, *bn3sq = st + 704;
  u16* wB1 = (u16*)(ws + 13276352);        // 7,168 u16
  u16* wB2 = (u16*)(ws + 13279936);        // 51,200 u16

  layout_prep_kernel<<<dim3(108, 64), 128, 0, stream>>>(image, c1w, c2w, lay8,
                                                        wB1, wB2, st);
  conv1_mfma<<<dim3(43, 2, 16), 128, 0, stream>>>(lay8, wB1, x1r, bn1sum,
                                                  bn1sq);
  conv2_lds<<<dim3(36, 64), 256, 0, stream>>>(x1r, wB2, bn1sum, bn1sq, bn1g,
                                              bn1b, x2b, bn2sum, bn2sq);
  bnapply2t_kernel<<<dim3(9, 64), 256, 0, stream>>>(x2b, bn2sum, bn2sq, bn2g,
                                                    bn2b, xB);
  fc1_mfma<<<dim3(72, 8), 256, 0, stream>>>(xB, f1w, fc1part);
  fc1_reduce_kernel<<<128, 256, 0, stream>>>(fc1part, fc1o, bn3sum, bn3sq);
  fc2_kernel<<<64, 64, 0, stream>>>(fc1o, bn3sum, bn3sq, bn3g, bn3b, f2w, f2b,
                                    (float*)d_out);
}